// Round 5
// baseline (228.823 us; speedup 1.0000x reference)
//
#include <hip/hip_runtime.h>
#include <math.h>

#define EPSV 1e-5f

typedef float f4v __attribute__((ext_vector_type(4)));

__device__ __forceinline__ float waveReduceSum(float v) {
#pragma unroll
    for (int o = 32; o > 0; o >>= 1) v += __shfl_down(v, o, 64);
    return v;
}

// ---------------------------------------------------------------------------
// K1: K[n,c] = elu(cls@wq.T + bq)+1 ; Q[n,c] = (elu(cls@wk.T + bk)+1)/16
//     Kw[n,c] = K * ln_w[c].  Block 0 also zeroes the sync counters (this
//     kernel completes before k_mega starts, stream-ordered).
__global__ void k_kq(const float* __restrict__ cls,
                     const float* __restrict__ wq, const float* __restrict__ bq,
                     const float* __restrict__ wk, const float* __restrict__ bk,
                     const float* __restrict__ ln_w,
                     float* __restrict__ Kb, float* __restrict__ Qb,
                     float* __restrict__ Kw, unsigned* __restrict__ cnt) {
    if (blockIdx.x == 0 && threadIdx.x < 64) cnt[threadIdx.x] = 0u;
    int w = blockIdx.x * 4 + (threadIdx.x >> 6); // 0..8191
    int lane = threadIdx.x & 63;
    int n = w >> 8, c = w & 255;
    const float* cp = cls + (size_t)n * 512;
    const float* qp = wq + (size_t)c * 512;
    const float* kp = wk + (size_t)c * 512;
    float aK = 0.f, aQ = 0.f;
#pragma unroll
    for (int i = 0; i < 8; ++i) {
        int kk = lane + i * 64;
        float cv = cp[kk];
        aK += cv * qp[kk];
        aQ += cv * kp[kk];
    }
    aK = waveReduceSum(aK);
    aQ = waveReduceSum(aQ);
    if (lane == 0) {
        float xk = aK + bq[c];
        float xq = aQ + bk[c];
        float Kv = (xk > 0.f ? xk : expf(xk) - 1.f) + 1.f;
        float Qv = ((xq > 0.f ? xq : expf(xq) - 1.f) + 1.f) * 0.0625f;
        Kb[w] = Kv;
        Qb[w] = Qv;
        Kw[w] = Kv * ln_w[c];
    }
}

// ---------------------------------------------------------------------------
// K2 (k_R): R[n,o] = sum_c conv_w[o,c]*Q[n,c].  grid 32, 256 thr.
__global__ void k_R(const float* __restrict__ Qb, const float* __restrict__ conv_w,
                    float* __restrict__ R) {
    int n = blockIdx.x, t = threadIdx.x;
    __shared__ float qs[256];
    qs[t] = Qb[n * 256 + t];
    __syncthreads();
    const float4* cw = (const float4*)(conv_w + (size_t)t * 256);
    const float4* q4 = (const float4*)qs;
    float acc = 0.f;
#pragma unroll 8
    for (int k = 0; k < 64; ++k) {
        float4 w4 = cw[k], v4 = q4[k];
        acc += w4.x * v4.x + w4.y * v4.y + w4.z * v4.z + w4.w * v4.w;
    }
    R[n * 256 + t] = acc;
}

// ---------------------------------------------------------------------------
// K3 (k_mega): fused pass1 + stats + s + alpha/beta + final.
// grid 512 = n*16+tile; 512 threads (8 waves); 2 blocks/CU co-resident.
// Phase A: read X (all 256 ch for this tile's 256 pixels), W -> LDS,
//          per-(n,g) partial sum/sumsq -> global; per-n barrier 1.
// Phase B: reduce stats, compute s in LDS + s-moment partials; barrier 2.
// Phase C: alpha/beta per o; out = s*alpha+beta+X (X re-read, L3-hot).
__global__ void __launch_bounds__(512, 4) k_mega(
        const float* __restrict__ X, const float* __restrict__ Kw,
        const float* __restrict__ Kb, const float* __restrict__ ln_b,
        const float* __restrict__ R, const float* __restrict__ conv_b,
        const float* __restrict__ gn_w, const float* __restrict__ gn_b,
        float* __restrict__ Sp, float* __restrict__ S2p,
        float* __restrict__ p1, float* __restrict__ p2,
        unsigned* __restrict__ cnt1, unsigned* __restrict__ cnt2,
        float* __restrict__ out) {
    int bid = blockIdx.x;
    int n = bid >> 4, tile = bid & 15;
    int t = threadIdx.x, wv = t >> 6, lane = t & 63;

    __shared__ float kws[256];
    __shared__ float Wlds[64][256];   // 64 KB
    __shared__ float ivs[64];
    __shared__ float sS[256];
    __shared__ float aS[256], bS[256];
    __shared__ float Rr[256];
    __shared__ float q1[4], q2[4];
    __shared__ float Bsh, Ms1s, Ms2s;

    if (t < 256) kws[t] = Kw[n * 256 + t];
    __syncthreads();

    int pix = tile * 256 + lane * 4;
    const float* xb = X + ((size_t)n * 256 << 12) + pix;

    // ---- Phase A: wave wv owns groups 8wv..8wv+7 (channels 32wv..32wv+31)
#pragma unroll
    for (int go = 0; go < 8; ++go) {
        int g = wv * 8 + go;
        int c0 = g * 4;
        float ax = 0.f, ay = 0.f, az = 0.f, aw = 0.f;
        float s = 0.f, s2 = 0.f;
#pragma unroll
        for (int j = 0; j < 4; ++j) {
            float4 v = *(const float4*)(xb + ((size_t)(c0 + j) << 12));
            float kv = kws[c0 + j];
            ax += kv * v.x; ay += kv * v.y; az += kv * v.z; aw += kv * v.w;
            s  += v.x + v.y + v.z + v.w;
            s2 += v.x * v.x + v.y * v.y + v.z * v.z + v.w * v.w;
        }
        float4 acc = {ax, ay, az, aw};
        *(float4*)(&Wlds[g][lane * 4]) = acc;
        s = waveReduceSum(s);
        s2 = waveReduceSum(s2);
        if (lane == 0) {
            Sp[bid * 64 + g] = s;
            S2p[bid * 64 + g] = s2;
        }
    }
    __threadfence();   // each writer's stores device-visible
    __syncthreads();
    if (t == 0) {
        atomicAdd(&cnt1[n], 1u);
        while (atomicAdd(&cnt1[n], 0u) < 16u) __builtin_amdgcn_s_sleep(8);
    }
    __syncthreads();

    // ---- Phase B: per-group stats + B (threads 0..63 = wave 0)
    if (t < 64) {
        float S = 0.f, S2 = 0.f;
#pragma unroll
        for (int tl = 0; tl < 16; ++tl) {
            S  += Sp[(n * 16 + tl) * 64 + t];
            S2 += S2p[(n * 16 + tl) * 64 + t];
        }
        float mu = S * (1.f / 16384.f);
        float var = S2 * (1.f / 16384.f) - mu * mu;
        float iv = rsqrtf(var + EPSV);
        ivs[t] = iv;
        float t1 = 0.f, t2 = 0.f;
#pragma unroll
        for (int j = 0; j < 4; ++j) {
            int c = t * 4 + j;
            t1 += Kb[n * 256 + c] * ln_b[c];
            t2 += kws[c];
        }
        float r = waveReduceSum(t1 - iv * mu * t2);
        if (t == 0) Bsh = r;
    }
    __syncthreads();

    // s per pixel: threads 0..255, one pixel each (stride-4B LDS, conflict-free)
    if (t < 256) {
        float s = Bsh;
#pragma unroll 16
        for (int g = 0; g < 64; ++g) s += ivs[g] * Wlds[g][t];
        sS[t] = s;
        float r1 = waveReduceSum(s);
        float r2 = waveReduceSum(s * s);
        if (lane == 0) { q1[wv] = r1; q2[wv] = r2; }
    }
    __syncthreads();
    if (t == 0) {
        p1[bid] = q1[0] + q1[1] + q1[2] + q1[3];
        p2[bid] = q2[0] + q2[1] + q2[2] + q2[3];
        __threadfence();
        atomicAdd(&cnt2[n], 1u);
        while (atomicAdd(&cnt2[n], 0u) < 16u) __builtin_amdgcn_s_sleep(8);
    }
    __syncthreads();

    // ---- Phase C: alpha/beta, then out = s*alpha + beta + X
    if (t == 0) {
        float a = 0.f, b = 0.f;
#pragma unroll
        for (int tl = 0; tl < 16; ++tl) { a += p1[n * 16 + tl]; b += p2[n * 16 + tl]; }
        Ms1s = a * (1.f / 4096.f);
        Ms2s = b * (1.f / 4096.f);
    }
    if (t < 256) Rr[t] = R[n * 256 + t];
    __syncthreads();
    if (t < 256) {
        int g4 = (t >> 2) << 2;
        float mR = 0.f, mR2 = 0.f, mRb = 0.f, mb = 0.f, mb2 = 0.f;
#pragma unroll
        for (int j = 0; j < 4; ++j) {
            float r = Rr[g4 + j];
            float bb = conv_b[g4 + j];
            mR += r; mR2 += r * r; mRb += r * bb; mb += bb; mb2 += bb * bb;
        }
        mR *= 0.25f; mR2 *= 0.25f; mRb *= 0.25f; mb *= 0.25f; mb2 *= 0.25f;
        float mu = Ms1s * mR + mb;
        float var = Ms2s * mR2 + 2.f * Ms1s * mRb + mb2 - mu * mu;
        float iv = rsqrtf(var + EPSV);
        aS[t] = Rr[t] * iv * gn_w[t];
        bS[t] = (conv_b[t] - mu) * iv * gn_w[t] + gn_b[t];
    }
    __syncthreads();

    float4 s4 = *(const float4*)(&sS[lane * 4]);
    const float* xo = X + ((size_t)n * 256 << 12) + pix;
    float* oo = out + ((size_t)n * 256 << 12) + pix;
#pragma unroll 4
    for (int j = 0; j < 32; ++j) {
        int o = wv * 32 + j;
        float4 x = *(const float4*)(xo + ((size_t)o << 12));
        float a = aS[o], b = bS[o];
        f4v r;
        r.x = fmaf(s4.x, a, b) + x.x;
        r.y = fmaf(s4.y, a, b) + x.y;
        r.z = fmaf(s4.z, a, b) + x.z;
        r.w = fmaf(s4.w, a, b) + x.w;
        __builtin_nontemporal_store(r, (f4v*)(oo + ((size_t)o << 12)));
    }
}

// ---------------------------------------------------------------------------
extern "C" void kernel_launch(void* const* d_in, const int* in_sizes, int n_in,
                              void* d_out, int out_size, void* d_ws, size_t ws_size,
                              hipStream_t stream) {
    const float* X      = (const float*)d_in[0];
    const float* cls    = (const float*)d_in[1];
    const float* ln_w   = (const float*)d_in[2];
    const float* ln_b   = (const float*)d_in[3];
    const float* wq     = (const float*)d_in[4];
    const float* bq     = (const float*)d_in[5];
    const float* wk     = (const float*)d_in[6];
    const float* bk     = (const float*)d_in[7];
    const float* conv_w = (const float*)d_in[8];
    const float* conv_b = (const float*)d_in[9];
    const float* gn_w   = (const float*)d_in[10];
    const float* gn_b   = (const float*)d_in[11];

    float* ws = (float*)d_ws;
    float* Kb   = ws;             // 8192
    float* Qb   = ws + 8192;      // 8192
    float* Kw   = ws + 16384;     // 8192
    float* R    = ws + 24576;     // 8192
    float* Sp   = ws + 32768;     // 32768
    float* S2p  = ws + 65536;     // 32768
    float* p1   = ws + 98304;     // 512
    float* p2   = ws + 98816;     // 512
    unsigned* cnt = (unsigned*)(ws + 99328); // 64 uints: cnt1[32], cnt2[32]

    k_kq<<<2048, 256, 0, stream>>>(cls, wq, bq, wk, bk, ln_w, Kb, Qb, Kw, cnt);
    k_R<<<32, 256, 0, stream>>>(Qb, conv_w, R);
    k_mega<<<512, 512, 0, stream>>>(X, Kw, Kb, ln_b, R, conv_b, gn_w, gn_b,
                                    Sp, S2p, p1, p2, cnt, cnt + 32,
                                    (float*)d_out);
}

// Round 6
// 197.666 us; speedup vs baseline: 1.1576x; 1.1576x over previous
//
#include <hip/hip_runtime.h>
#include <math.h>

#define EPSV 1e-5f

typedef float f4v __attribute__((ext_vector_type(4)));

__device__ __forceinline__ float waveReduceSum(float v) {
#pragma unroll
    for (int o = 32; o > 0; o >>= 1) v += __shfl_down(v, o, 64);
    return v;
}

// ---------------------------------------------------------------------------
// K1: K[n,c] = elu(cls@wq.T + bq)+1 ; Q[n,c] = (elu(cls@wk.T + bk)+1)/16
//     Kw[n,c] = K * ln_w[c].  Block 0 zeroes the (padded) sync counters.
__global__ void k_kq(const float* __restrict__ cls,
                     const float* __restrict__ wq, const float* __restrict__ bq,
                     const float* __restrict__ wk, const float* __restrict__ bk,
                     const float* __restrict__ ln_w,
                     float* __restrict__ Kb, float* __restrict__ Qb,
                     float* __restrict__ Kw, unsigned* __restrict__ cnt) {
    if (blockIdx.x == 0) {
        for (int i = threadIdx.x; i < 1024; i += 256) cnt[i] = 0u;
    }
    int w = blockIdx.x * 4 + (threadIdx.x >> 6); // 0..8191
    int lane = threadIdx.x & 63;
    int n = w >> 8, c = w & 255;
    const float* cp = cls + (size_t)n * 512;
    const float* qp = wq + (size_t)c * 512;
    const float* kp = wk + (size_t)c * 512;
    float aK = 0.f, aQ = 0.f;
#pragma unroll
    for (int i = 0; i < 8; ++i) {
        int kk = lane + i * 64;
        float cv = cp[kk];
        aK += cv * qp[kk];
        aQ += cv * kp[kk];
    }
    aK = waveReduceSum(aK);
    aQ = waveReduceSum(aQ);
    if (lane == 0) {
        float xk = aK + bq[c];
        float xq = aQ + bk[c];
        float Kv = (xk > 0.f ? xk : expf(xk) - 1.f) + 1.f;
        float Qv = ((xq > 0.f ? xq : expf(xq) - 1.f) + 1.f) * 0.0625f;
        Kb[w] = Kv;
        Qb[w] = Qv;
        Kw[w] = Kv * ln_w[c];
    }
}

// ---------------------------------------------------------------------------
// K2 (k_R): R[n,o] = sum_c conv_w[o,c]*Q[n,c].  grid 32, 256 thr.
__global__ void k_R(const float* __restrict__ Qb, const float* __restrict__ conv_w,
                    float* __restrict__ R) {
    int n = blockIdx.x, t = threadIdx.x;
    __shared__ float qs[256];
    qs[t] = Qb[n * 256 + t];
    __syncthreads();
    const float4* cw = (const float4*)(conv_w + (size_t)t * 256);
    const float4* q4 = (const float4*)qs;
    float acc = 0.f;
#pragma unroll 8
    for (int k = 0; k < 64; ++k) {
        float4 w4 = cw[k], v4 = q4[k];
        acc += w4.x * v4.x + w4.y * v4.y + w4.z * v4.z + w4.w * v4.w;
    }
    R[n * 256 + t] = acc;
}

// ---------------------------------------------------------------------------
// K3 (k_mega): fused pass1 + stats + s + alpha/beta + final.
// grid 512; n = bid&31 (same-n blocks share an XCD under bid%8 round-robin),
// tile = bid>>5. 512 threads (8 waves), 2 blocks/CU.
// Barrier poll = relaxed agent-scope LOAD (no RMW storm) + s_sleep(32).
__global__ void __launch_bounds__(512, 4) k_mega(
        const float* __restrict__ X, const float* __restrict__ Kw,
        const float* __restrict__ Kb, const float* __restrict__ ln_b,
        const float* __restrict__ R, const float* __restrict__ conv_b,
        const float* __restrict__ gn_w, const float* __restrict__ gn_b,
        float* __restrict__ Sp, float* __restrict__ S2p,
        float* __restrict__ p1, float* __restrict__ p2,
        unsigned* __restrict__ cnt,
        float* __restrict__ out) {
    int bid = blockIdx.x;
    int n = bid & 31, tile = bid >> 5;
    int t = threadIdx.x, wv = t >> 6, lane = t & 63;
    unsigned* c1 = cnt + n * 16;          // 64B-padded counter, barrier 1
    unsigned* c2 = cnt + 512 + n * 16;    // barrier 2

    __shared__ float kws[256];
    __shared__ float Wlds[64][256];   // 64 KB
    __shared__ float ivs[64];
    __shared__ float sS[256];
    __shared__ float aS[256], bS[256];
    __shared__ float Rr[256];
    __shared__ float q1[4], q2[4];
    __shared__ float Bsh, Ms1s, Ms2s;

    if (t < 256) kws[t] = Kw[n * 256 + t];
    __syncthreads();

    int pix = tile * 256 + lane * 4;
    const float* xb = X + ((size_t)n * 256 << 12) + pix;

    // ---- Phase A: wave wv owns groups 8wv..8wv+7 (channels 32wv..32wv+31)
#pragma unroll
    for (int go = 0; go < 8; ++go) {
        int g = wv * 8 + go;
        int c0 = g * 4;
        float ax = 0.f, ay = 0.f, az = 0.f, aw = 0.f;
        float s = 0.f, s2 = 0.f;
#pragma unroll
        for (int j = 0; j < 4; ++j) {
            float4 v = *(const float4*)(xb + ((size_t)(c0 + j) << 12));
            float kv = kws[c0 + j];
            ax += kv * v.x; ay += kv * v.y; az += kv * v.z; aw += kv * v.w;
            s  += v.x + v.y + v.z + v.w;
            s2 += v.x * v.x + v.y * v.y + v.z * v.z + v.w * v.w;
        }
        float4 acc = {ax, ay, az, aw};
        *(float4*)(&Wlds[g][lane * 4]) = acc;
        s = waveReduceSum(s);
        s2 = waveReduceSum(s2);
        if (lane == 0) {
            Sp[(n * 16 + tile) * 64 + g] = s;
            S2p[(n * 16 + tile) * 64 + g] = s2;
        }
    }
    __threadfence();
    __syncthreads();
    if (t == 0) {
        atomicAdd(c1, 1u);
        while (__hip_atomic_load(c1, __ATOMIC_RELAXED, __HIP_MEMORY_SCOPE_AGENT) < 16u)
            __builtin_amdgcn_s_sleep(32);
        __threadfence();
    }
    __syncthreads();

    // ---- Phase B: per-group stats + B (threads 0..63 = wave 0)
    if (t < 64) {
        float S = 0.f, S2 = 0.f;
#pragma unroll
        for (int tl = 0; tl < 16; ++tl) {
            S  += Sp[(n * 16 + tl) * 64 + t];
            S2 += S2p[(n * 16 + tl) * 64 + t];
        }
        float mu = S * (1.f / 16384.f);
        float var = S2 * (1.f / 16384.f) - mu * mu;
        float iv = rsqrtf(var + EPSV);
        ivs[t] = iv;
        float t1 = 0.f, t2 = 0.f;
#pragma unroll
        for (int j = 0; j < 4; ++j) {
            int c = t * 4 + j;
            t1 += Kb[n * 256 + c] * ln_b[c];
            t2 += kws[c];
        }
        float r = waveReduceSum(t1 - iv * mu * t2);
        if (t == 0) Bsh = r;
    }
    __syncthreads();

    // s per pixel: threads 0..255 (stride-4B LDS columns, conflict-free)
    if (t < 256) {
        float s = Bsh;
#pragma unroll 16
        for (int g = 0; g < 64; ++g) s += ivs[g] * Wlds[g][t];
        sS[t] = s;
        float r1 = waveReduceSum(s);
        float r2 = waveReduceSum(s * s);
        if (lane == 0) { q1[wv] = r1; q2[wv] = r2; }
    }
    __syncthreads();
    if (t == 0) {
        p1[n * 16 + tile] = q1[0] + q1[1] + q1[2] + q1[3];
        p2[n * 16 + tile] = q2[0] + q2[1] + q2[2] + q2[3];
        __threadfence();
        atomicAdd(c2, 1u);
        while (__hip_atomic_load(c2, __ATOMIC_RELAXED, __HIP_MEMORY_SCOPE_AGENT) < 16u)
            __builtin_amdgcn_s_sleep(32);
        __threadfence();
    }
    __syncthreads();

    // ---- Phase C: alpha/beta, then out = s*alpha + beta + X (X is L3-hot)
    if (t == 0) {
        float a = 0.f, b = 0.f;
#pragma unroll
        for (int tl = 0; tl < 16; ++tl) { a += p1[n * 16 + tl]; b += p2[n * 16 + tl]; }
        Ms1s = a * (1.f / 4096.f);
        Ms2s = b * (1.f / 4096.f);
    }
    if (t < 256) Rr[t] = R[n * 256 + t];
    __syncthreads();
    if (t < 256) {
        int g4 = (t >> 2) << 2;
        float mR = 0.f, mR2 = 0.f, mRb = 0.f, mb = 0.f, mb2 = 0.f;
#pragma unroll
        for (int j = 0; j < 4; ++j) {
            float r = Rr[g4 + j];
            float bb = conv_b[g4 + j];
            mR += r; mR2 += r * r; mRb += r * bb; mb += bb; mb2 += bb * bb;
        }
        mR *= 0.25f; mR2 *= 0.25f; mRb *= 0.25f; mb *= 0.25f; mb2 *= 0.25f;
        float mu = Ms1s * mR + mb;
        float var = Ms2s * mR2 + 2.f * Ms1s * mRb + mb2 - mu * mu;
        float iv = rsqrtf(var + EPSV);
        aS[t] = Rr[t] * iv * gn_w[t];
        bS[t] = (conv_b[t] - mu) * iv * gn_w[t] + gn_b[t];
    }
    __syncthreads();

    float4 s4 = *(const float4*)(&sS[lane * 4]);
    const float* xo = X + ((size_t)n * 256 << 12) + pix;
    float* oo = out + ((size_t)n * 256 << 12) + pix;
#pragma unroll 4
    for (int j = 0; j < 32; ++j) {
        int o = wv * 32 + j;
        float4 x = *(const float4*)(xo + ((size_t)o << 12));
        float a = aS[o], b = bS[o];
        f4v r;
        r.x = fmaf(s4.x, a, b) + x.x;
        r.y = fmaf(s4.y, a, b) + x.y;
        r.z = fmaf(s4.z, a, b) + x.z;
        r.w = fmaf(s4.w, a, b) + x.w;
        __builtin_nontemporal_store(r, (f4v*)(oo + ((size_t)o << 12)));
    }
}

// ---------------------------------------------------------------------------
extern "C" void kernel_launch(void* const* d_in, const int* in_sizes, int n_in,
                              void* d_out, int out_size, void* d_ws, size_t ws_size,
                              hipStream_t stream) {
    const float* X      = (const float*)d_in[0];
    const float* cls    = (const float*)d_in[1];
    const float* ln_w   = (const float*)d_in[2];
    const float* ln_b   = (const float*)d_in[3];
    const float* wq     = (const float*)d_in[4];
    const float* bq     = (const float*)d_in[5];
    const float* wk     = (const float*)d_in[6];
    const float* bk     = (const float*)d_in[7];
    const float* conv_w = (const float*)d_in[8];
    const float* conv_b = (const float*)d_in[9];
    const float* gn_w   = (const float*)d_in[10];
    const float* gn_b   = (const float*)d_in[11];

    float* ws = (float*)d_ws;
    float* Kb   = ws;             // 8192
    float* Qb   = ws + 8192;      // 8192
    float* Kw   = ws + 16384;     // 8192
    float* R    = ws + 24576;     // 8192
    float* Sp   = ws + 32768;     // 32768
    float* S2p  = ws + 65536;     // 32768
    float* p1   = ws + 98304;     // 512
    float* p2   = ws + 98816;     // 512
    unsigned* cnt = (unsigned*)(ws + 99328); // 1024 uints, 64B-padded pairs

    k_kq<<<2048, 256, 0, stream>>>(cls, wq, bq, wk, bk, ln_w, Kb, Qb, Kw, cnt);
    k_R<<<32, 256, 0, stream>>>(Qb, conv_w, R);
    k_mega<<<512, 512, 0, stream>>>(X, Kw, Kb, ln_b, R, conv_b, gn_w, gn_b,
                                    Sp, S2p, p1, p2, cnt, (float*)d_out);
}

// Round 7
// 95.380 us; speedup vs baseline: 2.3991x; 2.0724x over previous
//
#include <hip/hip_runtime.h>
#include <math.h>

#define EPSV 1e-5f

typedef float f4v __attribute__((ext_vector_type(4)));

__device__ __forceinline__ float waveReduceSum(float v) {
#pragma unroll
    for (int o = 32; o > 0; o >>= 1) v += __shfl_down(v, o, 64);
    return v;
}

// ---------------------------------------------------------------------------
// K1: K[n,c] = elu(cls@wq.T + bq)+1 ; Q[n,c] = (elu(cls@wk.T + bk)+1)/16
//     Kw[n,c] = K * ln_w[c]
// one wave per (n,c); 2048 blocks x 256 threads (4 waves each).  [R1-proven]
__global__ void k_kq(const float* __restrict__ cls,
                     const float* __restrict__ wq, const float* __restrict__ bq,
                     const float* __restrict__ wk, const float* __restrict__ bk,
                     const float* __restrict__ ln_w,
                     float* __restrict__ Kb, float* __restrict__ Qb,
                     float* __restrict__ Kw) {
    int w = blockIdx.x * 4 + (threadIdx.x >> 6); // 0..8191
    int lane = threadIdx.x & 63;
    int n = w >> 8, c = w & 255;
    const float* cp = cls + (size_t)n * 512;
    const float* qp = wq + (size_t)c * 512;
    const float* kp = wk + (size_t)c * 512;
    float aK = 0.f, aQ = 0.f;
#pragma unroll
    for (int i = 0; i < 8; ++i) {
        int kk = lane + i * 64;
        float cv = cp[kk];
        aK += cv * qp[kk];
        aQ += cv * kp[kk];
    }
    aK = waveReduceSum(aK);
    aQ = waveReduceSum(aQ);
    if (lane == 0) {
        float xk = aK + bq[c];
        float xq = aQ + bk[c];
        float Kv = (xk > 0.f ? xk : expf(xk) - 1.f) + 1.f;
        float Qv = ((xq > 0.f ? xq : expf(xq) - 1.f) + 1.f) * 0.0625f;
        Kb[w] = Kv;
        Qb[w] = Qv;
        Kw[w] = Kv * ln_w[c];
    }
}

// ---------------------------------------------------------------------------
// K2 (pass1): single HBM read of X producing
//   W[n,g,p] = sum_{c in g} Kw[n,c]*X[n,c,p]   (33.5 MB, stays in L2/L3)
//   Sp/S2p[block,g] = per-tile partial sum/sumsq of X over group channels
// grid 512 = n*16+tile; 512 threads (8 waves).  [R1-proven, untouched]
__global__ void __launch_bounds__(512) k_pass1(
        const float* __restrict__ X, const float* __restrict__ Kw,
        float* __restrict__ W, float* __restrict__ Sp, float* __restrict__ S2p) {
    int n = blockIdx.x >> 4, tile = blockIdx.x & 15;
    int wv = threadIdx.x >> 6, lane = threadIdx.x & 63;
    __shared__ float kws[256];
    if (threadIdx.x < 256) kws[threadIdx.x] = Kw[n * 256 + threadIdx.x];
    __syncthreads();
    int pix = tile * 256 + lane * 4;
    const float* xb = X + ((size_t)n * 256 << 12) + pix;
#pragma unroll
    for (int go = 0; go < 8; ++go) {
        int g = wv * 8 + go;
        int c0 = g * 4;
        float ax = 0.f, ay = 0.f, az = 0.f, aw = 0.f;
        float s = 0.f, s2 = 0.f;
#pragma unroll
        for (int j = 0; j < 4; ++j) {
            float4 v = *(const float4*)(xb + ((size_t)(c0 + j) << 12));
            float kv = kws[c0 + j];
            ax += kv * v.x; ay += kv * v.y; az += kv * v.z; aw += kv * v.w;
            s  += v.x + v.y + v.z + v.w;
            s2 += v.x * v.x + v.y * v.y + v.z * v.z + v.w * v.w;
        }
        float4 acc = {ax, ay, az, aw};
        *(float4*)(W + ((size_t)(n * 64 + g) << 12) + pix) = acc;
        s = waveReduceSum(s);
        s2 = waveReduceSum(s2);
        if (lane == 0) {
            Sp[blockIdx.x * 64 + g] = s;
            S2p[blockIdx.x * 64 + g] = s2;
        }
    }
}

// ---------------------------------------------------------------------------
// K3 (k_s): wave0 reduces Sp/S2p -> iv per group + B[n] inline; then all
// threads: s = sum_g iv_g*W_g + B; block moments.  [R3-proven, untouched]
// grid 128 = n*4+tile; 256 threads; thread handles one float4 (4 pixels).
__global__ void k_s(const float* __restrict__ W,
                    const float* __restrict__ Sp, const float* __restrict__ S2p,
                    const float* __restrict__ Kb, const float* __restrict__ Kw,
                    const float* __restrict__ ln_b,
                    float* __restrict__ sbuf,
                    float* __restrict__ p1, float* __restrict__ p2) {
    int n = blockIdx.x >> 2, tile = blockIdx.x & 3;
    int t = threadIdx.x;
    __shared__ float ivs[64];
    __shared__ float Bsh;
    __shared__ float q1[4], q2[4];
    if (t < 64) {
        float S = 0.f, S2 = 0.f;
#pragma unroll
        for (int tl = 0; tl < 16; ++tl) {
            S  += Sp[(n * 16 + tl) * 64 + t];
            S2 += S2p[(n * 16 + tl) * 64 + t];
        }
        float mu = S * (1.f / 16384.f);
        float var = S2 * (1.f / 16384.f) - mu * mu;
        float iv = rsqrtf(var + EPSV);
        ivs[t] = iv;
        float t1 = 0.f, t2 = 0.f;
#pragma unroll
        for (int j = 0; j < 4; ++j) {
            int c = t * 4 + j;
            t1 += Kb[n * 256 + c] * ln_b[c];
            t2 += Kw[n * 256 + c];
        }
        float r = waveReduceSum(t1 - iv * mu * t2);
        if (t == 0) Bsh = r;
    }
    __syncthreads();
    int pix = tile * 1024 + t * 4;
    const float* wb = W + ((size_t)n * 64 << 12) + pix;
    float Bn = Bsh;
    float sx = Bn, sy = Bn, sz = Bn, sw = Bn;
#pragma unroll 8
    for (int g = 0; g < 64; ++g) {
        float4 v = *(const float4*)(wb + ((size_t)g << 12));
        float iv = ivs[g];
        sx += iv * v.x; sy += iv * v.y; sz += iv * v.z; sw += iv * v.w;
    }
    float4 s4 = {sx, sy, sz, sw};
    *(float4*)(sbuf + n * 4096 + pix) = s4;
    float r1 = waveReduceSum(sx + sy + sz + sw);
    float r2 = waveReduceSum(sx * sx + sy * sy + sz * sz + sw * sw);
    int lane = t & 63, wid = t >> 6;
    if (lane == 0) { q1[wid] = r1; q2[wid] = r2; }
    __syncthreads();
    if (t == 0) {
        p1[blockIdx.x] = q1[0] + q1[1] + q1[2] + q1[3];
        p2[blockIdx.x] = q2[0] + q2[1] + q2[2] + q2[3];
    }
}

// ---------------------------------------------------------------------------
// K4 (k_ab): R = conv_w@Q (kept in LDS) + alpha/beta.  grid 32, 256 thr.
// [R3-proven, untouched]
__global__ void k_ab(const float* __restrict__ p1, const float* __restrict__ p2,
                     const float* __restrict__ Qb, const float* __restrict__ conv_w,
                     const float* __restrict__ conv_b,
                     const float* __restrict__ gn_w, const float* __restrict__ gn_b,
                     float* __restrict__ alpha, float* __restrict__ beta) {
    int n = blockIdx.x, t = threadIdx.x;
    __shared__ float qs[256];
    __shared__ float rs[256];
    __shared__ float Ms1s, Ms2s;
    qs[t] = Qb[n * 256 + t];
    if (t == 0) {
        float a = 0.f, b = 0.f;
#pragma unroll
        for (int i = 0; i < 4; ++i) { a += p1[n * 4 + i]; b += p2[n * 4 + i]; }
        Ms1s = a * (1.f / 4096.f);
        Ms2s = b * (1.f / 4096.f);
    }
    __syncthreads();
    const float4* cw = (const float4*)(conv_w + (size_t)t * 256);
    const float4* q4 = (const float4*)qs;
    float acc = 0.f;
#pragma unroll 8
    for (int k = 0; k < 64; ++k) {
        float4 w4 = cw[k], v4 = q4[k];
        acc += w4.x * v4.x + w4.y * v4.y + w4.z * v4.z + w4.w * v4.w;
    }
    rs[t] = acc;
    __syncthreads();
    float Ms1 = Ms1s, Ms2 = Ms2s;
    int g = t >> 2;
    float mR = 0.f, mR2 = 0.f, mRb = 0.f, mb = 0.f, mb2 = 0.f;
#pragma unroll
    for (int j = 0; j < 4; ++j) {
        float r = rs[g * 4 + j];
        float bb = conv_b[g * 4 + j];
        mR += r; mR2 += r * r; mRb += r * bb; mb += bb; mb2 += bb * bb;
    }
    mR *= 0.25f; mR2 *= 0.25f; mRb *= 0.25f; mb *= 0.25f; mb2 *= 0.25f;
    float mu = Ms1 * mR + mb;
    float var = Ms2 * mR2 + 2.f * Ms1 * mRb + mb2 - mu * mu;
    float iv = rsqrtf(var + EPSV);
    alpha[n * 256 + t] = acc * iv * gn_w[t];
    beta[n * 256 + t] = (conv_b[t] - mu) * iv * gn_w[t] + gn_b[t];
}

// ---------------------------------------------------------------------------
// K5 (k_final v2): out = s*alpha + beta + X.
// Each thread: one pixel-quad reused across 8 consecutive o-planes ->
// 1 sbuf load + 8 X loads + 8 plain stores (8 independent 1KB-coalesced
// streams per wave for MLP; no NT — out is never re-read, X is dead after).
// grid 4096 = ((n*32 + ot)*4 + pt); 256 threads.
__global__ void __launch_bounds__(256) k_final(
        const float* __restrict__ X, const float* __restrict__ sbuf,
        const float* __restrict__ alpha, const float* __restrict__ beta,
        float* __restrict__ out) {
    int bid = blockIdx.x;
    int pt = bid & 3;
    int ot = (bid >> 2) & 31;
    int n = bid >> 7;
    int t = threadIdx.x;
    int px = pt * 1024 + t * 4;
    int o0 = ot * 8;
    float4 s4 = *(const float4*)(sbuf + n * 4096 + px);
    const float* xb = X + ((size_t)(n * 256 + o0) << 12) + px;
    float* ob = out + ((size_t)(n * 256 + o0) << 12) + px;
#pragma unroll
    for (int j = 0; j < 8; ++j) {
        float a = alpha[n * 256 + o0 + j];
        float b = beta[n * 256 + o0 + j];
        float4 x = *(const float4*)(xb + ((size_t)j << 12));
        f4v r;
        r.x = fmaf(s4.x, a, b) + x.x;
        r.y = fmaf(s4.y, a, b) + x.y;
        r.z = fmaf(s4.z, a, b) + x.z;
        r.w = fmaf(s4.w, a, b) + x.w;
        *(f4v*)(ob + ((size_t)j << 12)) = r;
    }
}

// ---------------------------------------------------------------------------
extern "C" void kernel_launch(void* const* d_in, const int* in_sizes, int n_in,
                              void* d_out, int out_size, void* d_ws, size_t ws_size,
                              hipStream_t stream) {
    const float* X      = (const float*)d_in[0];
    const float* cls    = (const float*)d_in[1];
    const float* ln_w   = (const float*)d_in[2];
    const float* ln_b   = (const float*)d_in[3];
    const float* wq     = (const float*)d_in[4];
    const float* bq     = (const float*)d_in[5];
    const float* wk     = (const float*)d_in[6];
    const float* bk     = (const float*)d_in[7];
    const float* conv_w = (const float*)d_in[8];
    const float* conv_b = (const float*)d_in[9];
    const float* gn_w   = (const float*)d_in[10];
    const float* gn_b   = (const float*)d_in[11];

    float* ws = (float*)d_ws;
    float* Kb    = ws;            // 8192
    float* Qb    = ws + 8192;     // 8192
    float* Kw    = ws + 16384;    // 8192
    float* Sp    = ws + 24576;    // 32768
    float* S2p   = ws + 57344;    // 32768
    float* p1    = ws + 90112;    // 128
    float* p2    = ws + 90240;    // 128
    float* alpha = ws + 90368;    // 8192
    float* beta  = ws + 98560;    // 8192
    float* sbuf  = ws + 131072;   // 131072 (16B aligned)
    float* W     = ws + 262144;   // 8,388,608 (33.5 MB)

    k_kq<<<2048, 256, 0, stream>>>(cls, wq, bq, wk, bk, ln_w, Kb, Qb, Kw);
    k_pass1<<<512, 512, 0, stream>>>(X, Kw, W, Sp, S2p);
    k_s<<<128, 256, 0, stream>>>(W, Sp, S2p, Kb, Kw, ln_b, sbuf, p1, p2);
    k_ab<<<32, 256, 0, stream>>>(p1, p2, Qb, conv_w, conv_b, gn_w, gn_b, alpha, beta);
    k_final<<<4096, 256, 0, stream>>>(X, sbuf, alpha, beta, (float*)d_out);
}

// Round 8
// 91.959 us; speedup vs baseline: 2.4883x; 1.0372x over previous
//
#include <hip/hip_runtime.h>
#include <math.h>

#define EPSV 1e-5f

typedef float f4v __attribute__((ext_vector_type(4)));

__device__ __forceinline__ float waveReduceSum(float v) {
#pragma unroll
    for (int o = 32; o > 0; o >>= 1) v += __shfl_down(v, o, 64);
    return v;
}

// ---------------------------------------------------------------------------
// K1: K[n,c] = elu(cls@wq.T + bq)+1 ; Q[n,c] = (elu(cls@wk.T + bk)+1)/16
//     Kw[n,c] = K * ln_w[c]
// one wave per (n,c); 2048 blocks x 256 threads (4 waves each).  [R1-proven]
__global__ void k_kq(const float* __restrict__ cls,
                     const float* __restrict__ wq, const float* __restrict__ bq,
                     const float* __restrict__ wk, const float* __restrict__ bk,
                     const float* __restrict__ ln_w,
                     float* __restrict__ Kb, float* __restrict__ Qb,
                     float* __restrict__ Kw) {
    int w = blockIdx.x * 4 + (threadIdx.x >> 6); // 0..8191
    int lane = threadIdx.x & 63;
    int n = w >> 8, c = w & 255;
    const float* cp = cls + (size_t)n * 512;
    const float* qp = wq + (size_t)c * 512;
    const float* kp = wk + (size_t)c * 512;
    float aK = 0.f, aQ = 0.f;
#pragma unroll
    for (int i = 0; i < 8; ++i) {
        int kk = lane + i * 64;
        float cv = cp[kk];
        aK += cv * qp[kk];
        aQ += cv * kp[kk];
    }
    aK = waveReduceSum(aK);
    aQ = waveReduceSum(aQ);
    if (lane == 0) {
        float xk = aK + bq[c];
        float xq = aQ + bk[c];
        float Kv = (xk > 0.f ? xk : expf(xk) - 1.f) + 1.f;
        float Qv = ((xq > 0.f ? xq : expf(xq) - 1.f) + 1.f) * 0.0625f;
        Kb[w] = Kv;
        Qb[w] = Qv;
        Kw[w] = Kv * ln_w[c];
    }
}

// ---------------------------------------------------------------------------
// K2 (pass1): single HBM read of X producing
//   W[n,g,p] = sum_{c in g} Kw[n,c]*X[n,c,p]   (33.5 MB, stays in L2/L3)
//   Sp/S2p[block,g] = per-tile partial sum/sumsq of X over group channels
// grid 512 = n*16+tile; 512 threads (8 waves).  [R1-proven, untouched]
__global__ void __launch_bounds__(512) k_pass1(
        const float* __restrict__ X, const float* __restrict__ Kw,
        float* __restrict__ W, float* __restrict__ Sp, float* __restrict__ S2p) {
    int n = blockIdx.x >> 4, tile = blockIdx.x & 15;
    int wv = threadIdx.x >> 6, lane = threadIdx.x & 63;
    __shared__ float kws[256];
    if (threadIdx.x < 256) kws[threadIdx.x] = Kw[n * 256 + threadIdx.x];
    __syncthreads();
    int pix = tile * 256 + lane * 4;
    const float* xb = X + ((size_t)n * 256 << 12) + pix;
#pragma unroll
    for (int go = 0; go < 8; ++go) {
        int g = wv * 8 + go;
        int c0 = g * 4;
        float ax = 0.f, ay = 0.f, az = 0.f, aw = 0.f;
        float s = 0.f, s2 = 0.f;
#pragma unroll
        for (int j = 0; j < 4; ++j) {
            float4 v = *(const float4*)(xb + ((size_t)(c0 + j) << 12));
            float kv = kws[c0 + j];
            ax += kv * v.x; ay += kv * v.y; az += kv * v.z; aw += kv * v.w;
            s  += v.x + v.y + v.z + v.w;
            s2 += v.x * v.x + v.y * v.y + v.z * v.z + v.w * v.w;
        }
        float4 acc = {ax, ay, az, aw};
        *(float4*)(W + ((size_t)(n * 64 + g) << 12) + pix) = acc;
        s = waveReduceSum(s);
        s2 = waveReduceSum(s2);
        if (lane == 0) {
            Sp[blockIdx.x * 64 + g] = s;
            S2p[blockIdx.x * 64 + g] = s2;
        }
    }
}

// ---------------------------------------------------------------------------
// K3 (k_s): wave0 reduces Sp/S2p -> iv per group + B[n] inline; all threads:
// s = sum_g iv_g*W_g + B (float2/thread); block s-moment partials.
// tile==0 blocks additionally compute R[n,:] = conv_w @ Q.
// grid 256 = n*8+tile; 256 threads; thread handles one float2 (2 pixels).
__global__ void k_s(const float* __restrict__ W,
                    const float* __restrict__ Sp, const float* __restrict__ S2p,
                    const float* __restrict__ Kb, const float* __restrict__ Kw,
                    const float* __restrict__ ln_b,
                    const float* __restrict__ Qb, const float* __restrict__ conv_w,
                    float* __restrict__ sbuf,
                    float* __restrict__ p1, float* __restrict__ p2,
                    float* __restrict__ R) {
    int n = blockIdx.x >> 3, tile = blockIdx.x & 7;
    int t = threadIdx.x;
    __shared__ float ivs[64];
    __shared__ float Bsh;
    __shared__ float q1[4], q2[4];
    __shared__ float qs[256];
    if (t < 64) {
        float S = 0.f, S2 = 0.f;
#pragma unroll
        for (int tl = 0; tl < 16; ++tl) {
            S  += Sp[(n * 16 + tl) * 64 + t];
            S2 += S2p[(n * 16 + tl) * 64 + t];
        }
        float mu = S * (1.f / 16384.f);
        float var = S2 * (1.f / 16384.f) - mu * mu;
        float iv = rsqrtf(var + EPSV);
        ivs[t] = iv;
        float t1 = 0.f, t2 = 0.f;
#pragma unroll
        for (int j = 0; j < 4; ++j) {
            int c = t * 4 + j;
            t1 += Kb[n * 256 + c] * ln_b[c];
            t2 += Kw[n * 256 + c];
        }
        float r = waveReduceSum(t1 - iv * mu * t2);
        if (t == 0) Bsh = r;
    }
    __syncthreads();
    int pix = tile * 512 + t * 2;
    const float* wb = W + ((size_t)n * 64 << 12) + pix;
    float Bn = Bsh;
    float sx = Bn, sy = Bn;
#pragma unroll 16
    for (int g = 0; g < 64; ++g) {
        float2 v = *(const float2*)(wb + ((size_t)g << 12));
        float iv = ivs[g];
        sx += iv * v.x; sy += iv * v.y;
    }
    float2 s2v = {sx, sy};
    *(float2*)(sbuf + n * 4096 + pix) = s2v;
    float r1 = waveReduceSum(sx + sy);
    float r2 = waveReduceSum(sx * sx + sy * sy);
    int lane = t & 63, wid = t >> 6;
    if (lane == 0) { q1[wid] = r1; q2[wid] = r2; }
    __syncthreads();
    if (t == 0) {
        p1[blockIdx.x] = q1[0] + q1[1] + q1[2] + q1[3];
        p2[blockIdx.x] = q2[0] + q2[1] + q2[2] + q2[3];
    }
    if (tile == 0) {
        qs[t] = Qb[n * 256 + t];
        __syncthreads();
        const float4* cw = (const float4*)(conv_w + (size_t)t * 256);
        const float4* q4 = (const float4*)qs;
        float acc = 0.f;
#pragma unroll 8
        for (int k = 0; k < 64; ++k) {
            float4 w4 = cw[k], v4 = q4[k];
            acc += w4.x * v4.x + w4.y * v4.y + w4.z * v4.z + w4.w * v4.w;
        }
        R[n * 256 + t] = acc;
    }
}

// ---------------------------------------------------------------------------
// K4 (k_final): flat layout [R3-proven] + inline alpha/beta (o is uniform
// per block: 1024 consecutive elems = 1/4 of one o-plane). NT store.
// grid 32768 x 256.
__global__ void __launch_bounds__(256) k_final(
        const float* __restrict__ X, const float* __restrict__ sbuf,
        const float* __restrict__ p1, const float* __restrict__ p2,
        const float* __restrict__ R, const float* __restrict__ conv_b,
        const float* __restrict__ gn_w, const float* __restrict__ gn_b,
        float* __restrict__ out) {
    size_t idx4 = (size_t)blockIdx.x * 256 + threadIdx.x;
    size_t e0 = (size_t)blockIdx.x * 1024;   // block-uniform
    int n = (int)(e0 >> 20);
    int o = (int)((e0 & 1048575) >> 12);     // uniform within block

    // inline alpha/beta (uniform scalar work, ~25 loads)
    float a1 = 0.f, a2 = 0.f;
#pragma unroll
    for (int i = 0; i < 8; ++i) { a1 += p1[n * 8 + i]; a2 += p2[n * 8 + i]; }
    float Ms1 = a1 * (1.f / 4096.f);
    float Ms2 = a2 * (1.f / 4096.f);
    int g4 = o & ~3;
    float mR = 0.f, mR2 = 0.f, mRb = 0.f, mb = 0.f, mb2 = 0.f;
#pragma unroll
    for (int j = 0; j < 4; ++j) {
        float r = R[n * 256 + g4 + j];
        float bb = conv_b[g4 + j];
        mR += r; mR2 += r * r; mRb += r * bb; mb += bb; mb2 += bb * bb;
    }
    mR *= 0.25f; mR2 *= 0.25f; mRb *= 0.25f; mb *= 0.25f; mb2 *= 0.25f;
    float mu = Ms1 * mR + mb;
    float var = Ms2 * mR2 + 2.f * Ms1 * mRb + mb2 - mu * mu;
    float iv = rsqrtf(var + EPSV);
    float gw = gn_w[o];
    float a = R[n * 256 + o] * iv * gw;
    float b = (conv_b[o] - mu) * iv * gw + gn_b[o];

    size_t e = idx4 * 4;
    int pix = (int)(e & 4095);
    float4 x = ((const float4*)X)[idx4];
    float4 s = *(const float4*)(sbuf + n * 4096 + pix);
    f4v r;
    r.x = fmaf(s.x, a, b) + x.x;
    r.y = fmaf(s.y, a, b) + x.y;
    r.z = fmaf(s.z, a, b) + x.z;
    r.w = fmaf(s.w, a, b) + x.w;
    __builtin_nontemporal_store(r, (f4v*)out + idx4);
}

// ---------------------------------------------------------------------------
extern "C" void kernel_launch(void* const* d_in, const int* in_sizes, int n_in,
                              void* d_out, int out_size, void* d_ws, size_t ws_size,
                              hipStream_t stream) {
    const float* X      = (const float*)d_in[0];
    const float* cls    = (const float*)d_in[1];
    const float* ln_w   = (const float*)d_in[2];
    const float* ln_b   = (const float*)d_in[3];
    const float* wq     = (const float*)d_in[4];
    const float* bq     = (const float*)d_in[5];
    const float* wk     = (const float*)d_in[6];
    const float* bk     = (const float*)d_in[7];
    const float* conv_w = (const float*)d_in[8];
    const float* conv_b = (const float*)d_in[9];
    const float* gn_w   = (const float*)d_in[10];
    const float* gn_b   = (const float*)d_in[11];

    float* ws = (float*)d_ws;
    float* Kb    = ws;            // 8192
    float* Qb    = ws + 8192;     // 8192
    float* Kw    = ws + 16384;    // 8192
    float* Sp    = ws + 24576;    // 32768
    float* S2p   = ws + 57344;    // 32768
    float* p1    = ws + 90112;    // 256
    float* p2    = ws + 90368;    // 256
    float* R     = ws + 90624;    // 8192
    float* sbuf  = ws + 131072;   // 131072 (16B aligned)
    float* W     = ws + 262144;   // 8,388,608 (33.5 MB)

    k_kq<<<2048, 256, 0, stream>>>(cls, wq, bq, wk, bk, ln_w, Kb, Qb, Kw);
    k_pass1<<<512, 512, 0, stream>>>(X, Kw, W, Sp, S2p);
    k_s<<<256, 256, 0, stream>>>(W, Sp, S2p, Kb, Kw, ln_b, Qb, conv_w,
                                 sbuf, p1, p2, R);
    k_final<<<32768, 256, 0, stream>>>(X, sbuf, p1, p2, R, conv_b, gn_w, gn_b,
                                       (float*)d_out);
}